// Round 1
// baseline (884.822 us; speedup 1.0000x reference)
//
#include <hip/hip_runtime.h>
#include <math.h>

// Problem constants
#define BATCH 32768
#define EMB   2048
#define KDIM  320      // 5*8*8
#define KACT  103      // ceil(0.05*2048)

// GEMM tiling: 1024 threads, 16 rows x 2048 cols per block, 2 cols/thread.
// Rationale (r4/r5/r6 post-mortems): throughput tracks resident waves; the
// only way to 8 waves/SIMD is total regs <= 64 -> acc[16][2] (32) + no
// manual B prefetch. A values live in SGPRs (uniform s_load) and feed
// v_fma_f32 directly, costing zero VGPRs.
#define BM 16
#define GTHREADS 1024

// Conv batching (== BM so one conv block produces exactly one A-tile)
#define CIMG 16

// ---------------------------------------------------------------------------
// Kernel 0: transpose fc_w (2048 x 320) -> WT (320 x 2048).
// ---------------------------------------------------------------------------
__global__ __launch_bounds__(256) void transpose_w_kernel(const float* __restrict__ W,
                                                          float* __restrict__ WT) {
  __shared__ float tile[32][33];
  const int k0 = blockIdx.x * 32;
  const int n0 = blockIdx.y * 32;
  const int tx = threadIdx.x;
  const int ty = threadIdx.y;
  for (int i = ty; i < 32; i += 8)
    tile[i][tx] = W[(size_t)(n0 + i) * KDIM + k0 + tx];
  __syncthreads();
  for (int i = ty; i < 32; i += 8)
    WT[(size_t)(k0 + i) * EMB + n0 + tx] = tile[tx][i];
}

// ---------------------------------------------------------------------------
// Kernel 1: conv3x3(valid) + batchnorm + relu + maxpool3x3 stride3 (valid).
// (unchanged — correct, residual-neutral)
// 16 images per 512-thread block; tile-major contiguous A-tile output.
// ---------------------------------------------------------------------------
__global__ __launch_bounds__(512) void conv_pool_kernel(const float* __restrict__ x,
                                                        const float* __restrict__ cw,
                                                        const float* __restrict__ gamma,
                                                        const float* __restrict__ beta,
                                                        const float* __restrict__ mean,
                                                        const float* __restrict__ var,
                                                        float* __restrict__ Ht) {
#pragma clang fp contract(off)
  __shared__ float xs[CIMG * 784];       // 50 KB
  __shared__ float hs[KDIM * 17];        // k-major staging, stride 17
  __shared__ float wv[45];
  __shared__ float inv_s[5], mu_s[5], be_s[5];
  const int t  = threadIdx.x;
  const int b0 = blockIdx.x * CIMG;

  {
    const float4* src = (const float4*)(x + (size_t)b0 * 784);
    float4* dst = (float4*)xs;
    for (int i = t; i < CIMG * 196; i += 512) dst[i] = src[i];
  }
  if (t < 45) wv[t] = cw[t];
  if (t < 5) {
    inv_s[t] = gamma[t] / sqrtf(var[t] + 1e-5f);  // IEEE div & sqrt
    mu_s[t] = mean[t];
    be_s[t] = beta[t];
  }
  __syncthreads();

  const int i0   = t >> 6;
  const int lane = t & 63;
  const int py = lane >> 3;
  const int px = lane & 7;

  for (int ii = 0; ii < 2; ++ii) {
    const int img = i0 * 2 + ii;
    const float* xb = xs + img * 784;

    float xr[5][5];
#pragma unroll
    for (int i = 0; i < 5; ++i)
#pragma unroll
      for (int j = 0; j < 5; ++j)
        xr[i][j] = xb[(3 * py + i) * 28 + 3 * px + j];

#pragma unroll
    for (int c = 0; c < 5; ++c) {
      float wr[9];
#pragma unroll
      for (int i = 0; i < 9; ++i) wr[i] = wv[c * 9 + i];
      const float inv = inv_s[c], mu = mu_s[c], be = be_s[c];
      float mx = -__builtin_huge_valf();
#pragma unroll
      for (int ry = 0; ry < 3; ++ry)
#pragma unroll
        for (int rx = 0; rx < 3; ++rx) {
          float s = 0.0f;
#pragma unroll
          for (int di = 0; di < 3; ++di)
#pragma unroll
            for (int dj = 0; dj < 3; ++dj)
              s = __builtin_fmaf(xr[ry + di][rx + dj], wr[di * 3 + dj], s);
          float t1 = s - mu;
          float t2 = t1 * inv;
          float t3 = t2 + be;
          mx = fmaxf(mx, t3);
        }
      hs[(c * 64 + lane) * 17 + img] = fmaxf(mx, 0.0f);
    }
  }
  __syncthreads();

  float* dst = Ht + (size_t)blockIdx.x * (KDIM * CIMG);
  for (int i = t; i < KDIM * CIMG; i += 512) {
    const int k = i >> 4;
    const int img = i & 15;
    dst[i] = hs[k * 17 + img];
  }
}

// ---------------------------------------------------------------------------
// Kernel 2: fused GEMM + per-row rank-103 threshold + binary write.
// Main loop unchanged (bit-identical acc): 1024 threads, 2 cols/thread,
// A via uniform s_load, __launch_bounds__(1024, 8) -> 8 waves/SIMD.
//
// Epilogue v2 (this round): the 4-pass radix-256 histogram (128 LDS atomics
// per thread, SQ_LDS_BANK_CONFLICT=2.9e7) is replaced by a wave-local EXACT
// bisection select:
//   - transpose acc through a 64 KB LDS buffer, 8 rows per phase, so each
//     wave owns one full row (32 values/lane in VGPRs);
//   - MSB-first binary search of the sign-flipped uint key: 32 steps, each
//     step = 32 x (v_cmp + __ballot -> s_bcnt1). Count and search state are
//     wave-uniform (SGPRs); zero atomics, zero histograms.
// T = max{T : count(u>=T) >= 103} is exactly the 103rd-largest key, and
// (u >= T) reproduces the reference tie semantics (z >= topv[:,-1]).
// Phase order stores acc hi-half to LDS BEFORE loading v[32] so peak VGPR
// stays ~56 < 64 (no spill, occupancy preserved).
// ---------------------------------------------------------------------------
__global__ __launch_bounds__(GTHREADS, 8) void gemm_topk_kernel(const float* __restrict__ Ht,
                                                                const float* __restrict__ WT,
                                                                float* __restrict__ out) {
  __shared__ float zb[8][EMB];          // 64 KB row buffer (two phases)
  __shared__ unsigned thr_s[BM];

  const int t    = threadIdx.x;
  const int lane = t & 63;
  const int w    = t >> 6;               // wave 0..15
  const int m0   = blockIdx.x * BM;
  const int nt   = t * 2;                // 2 columns per thread

  float acc[BM][2];
#pragma unroll
  for (int m = 0; m < BM; ++m) {
    acc[m][0] = 0.0f;
    acc[m][1] = 0.0f;
  }

  const float* Ap = Ht + (size_t)blockIdx.x * (KDIM * BM);  // A(k,m)=Ap[k*16+m]
  const float* wp = WT + nt;

#pragma unroll 4
  for (int k = 0; k < KDIM; ++k) {
    const float* ak = Ap + (size_t)k * BM;
    float av[BM];
#pragma unroll
    for (int m = 0; m < BM; ++m) av[m] = ak[m];   // uniform -> s_load (SGPRs)
    const float2 bb = *(const float2*)(wp + (size_t)k * EMB);
#pragma unroll
    for (int m = 0; m < BM; ++m) {
      acc[m][0] = __builtin_fmaf(av[m], bb.x, acc[m][0]);
      acc[m][1] = __builtin_fmaf(av[m], bb.y, acc[m][1]);
    }
  }

  // ==== phase A: rows 8..15 (store first -> acc hi-half dies, frees VGPRs)
#pragma unroll
  for (int m = 0; m < 8; ++m)
    *(float2*)&zb[m][nt] = *(const float2*)&acc[8 + m][0];
  __syncthreads();

  if (w >= 8) {
    const unsigned* row = (const unsigned*)&zb[w - 8][0];
    unsigned v[32];
#pragma unroll
    for (int j = 0; j < 32; ++j) {
      const unsigned x = row[j * 64 + lane];   // stride-64: bank = lane%32, conflict-free
      v[j] = x ^ (unsigned)(((int)x >> 31) | 0x80000000);  // ascending order map
    }
    unsigned T = 0u;
    for (int b = 31; b >= 0; --b) {
      const unsigned cand = T | (1u << b);
      unsigned cnt = 0u;
#pragma unroll
      for (int j = 0; j < 32; ++j)
        cnt += (unsigned)__popcll(__ballot(v[j] >= cand));
      if (cnt >= KACT) T = cand;               // wave-uniform (SGPR) update
    }
    if (lane == 0) thr_s[w] = T;               // thr for row m0 + w  (w in 8..15)
  }
  __syncthreads();

#pragma unroll
  for (int m = 0; m < 8; ++m) {
    const float2 p = *(const float2*)&zb[m][nt];
    const unsigned thr = thr_s[8 + m];
    unsigned ux = __float_as_uint(p.x); ux ^= (unsigned)(((int)ux >> 31) | 0x80000000);
    unsigned uy = __float_as_uint(p.y); uy ^= (unsigned)(((int)uy >> 31) | 0x80000000);
    float2 o;
    o.x = (ux >= thr) ? 1.0f : 0.0f;           // tie semantics: z >= topv[:,-1]
    o.y = (uy >= thr) ? 1.0f : 0.0f;
    *(float2*)(out + (size_t)(m0 + 8 + m) * EMB + nt) = o;
  }
  __syncthreads();   // all reads of zb done before phase B overwrites

  // ==== phase B: rows 0..7
#pragma unroll
  for (int m = 0; m < 8; ++m)
    *(float2*)&zb[m][nt] = *(const float2*)&acc[m][0];
  __syncthreads();

  if (w < 8) {
    const unsigned* row = (const unsigned*)&zb[w][0];
    unsigned v[32];
#pragma unroll
    for (int j = 0; j < 32; ++j) {
      const unsigned x = row[j * 64 + lane];
      v[j] = x ^ (unsigned)(((int)x >> 31) | 0x80000000);
    }
    unsigned T = 0u;
    for (int b = 31; b >= 0; --b) {
      const unsigned cand = T | (1u << b);
      unsigned cnt = 0u;
#pragma unroll
      for (int j = 0; j < 32; ++j)
        cnt += (unsigned)__popcll(__ballot(v[j] >= cand));
      if (cnt >= KACT) T = cand;
    }
    if (lane == 0) thr_s[w] = T;               // thr for row m0 + w  (w in 0..7)
  }
  __syncthreads();

#pragma unroll
  for (int m = 0; m < 8; ++m) {
    const float2 p = *(const float2*)&zb[m][nt];
    const unsigned thr = thr_s[m];
    unsigned ux = __float_as_uint(p.x); ux ^= (unsigned)(((int)ux >> 31) | 0x80000000);
    unsigned uy = __float_as_uint(p.y); uy ^= (unsigned)(((int)uy >> 31) | 0x80000000);
    float2 o;
    o.x = (ux >= thr) ? 1.0f : 0.0f;
    o.y = (uy >= thr) ? 1.0f : 0.0f;
    *(float2*)(out + (size_t)(m0 + m) * EMB + nt) = o;
  }
}

// ---------------------------------------------------------------------------
extern "C" void kernel_launch(void* const* d_in, const int* in_sizes, int n_in,
                              void* d_out, int out_size, void* d_ws, size_t ws_size,
                              hipStream_t stream) {
  const float* x      = (const float*)d_in[0];
  const float* conv_w = (const float*)d_in[1];
  const float* gamma  = (const float*)d_in[2];
  const float* beta   = (const float*)d_in[3];
  const float* mean   = (const float*)d_in[4];
  const float* var    = (const float*)d_in[5];
  const float* fc_w   = (const float*)d_in[6];
  float* out = (float*)d_out;

  // workspace: Ht tile-major (2048 tiles x 320 x 16 f32 = 40 MB) | WT (320x2048)
  float* Ht = (float*)d_ws;
  float* WT = (float*)d_ws + (size_t)KDIM * BATCH;

  transpose_w_kernel<<<dim3(KDIM / 32, EMB / 32), dim3(32, 8), 0, stream>>>(fc_w, WT);
  conv_pool_kernel<<<BATCH / CIMG, 512, 0, stream>>>(x, conv_w, gamma, beta, mean, var, Ht);
  gemm_topk_kernel<<<BATCH / BM, GTHREADS, 0, stream>>>(Ht, WT, out);
}

// Round 2
// 823.954 us; speedup vs baseline: 1.0739x; 1.0739x over previous
//
#include <hip/hip_runtime.h>
#include <math.h>

// Problem constants
#define BATCH 32768
#define EMB   2048
#define KDIM  320      // 5*8*8
#define KACT  103      // ceil(0.05*2048)

// GEMM tiling: 1024 threads, 16 rows x 2048 cols per block, 2 cols/thread.
// A in SGPRs (uniform s_load), acc[16][2]=32 VGPRs, 8 waves/SIMD.
#define BM 16
#define GTHREADS 1024

// Conv batching (== BM so one block produces exactly its own A-tile)
#define CIMG 16

typedef unsigned uint32x4 __attribute__((ext_vector_type(4)));

// ---------------------------------------------------------------------------
// Kernel 0: transpose fc_w (2048 x 320) -> WT (320 x 2048).  (unchanged)
// ---------------------------------------------------------------------------
__global__ __launch_bounds__(256) void transpose_w_kernel(const float* __restrict__ W,
                                                          float* __restrict__ WT) {
  __shared__ float tile[32][33];
  const int k0 = blockIdx.x * 32;
  const int n0 = blockIdx.y * 32;
  const int tx = threadIdx.x;
  const int ty = threadIdx.y;
  for (int i = ty; i < 32; i += 8)
    tile[i][tx] = W[(size_t)(n0 + i) * KDIM + k0 + tx];
  __syncthreads();
  for (int i = ty; i < 32; i += 8)
    WT[(size_t)(k0 + i) * EMB + n0 + tx] = tile[tx][i];
}

// ---------------------------------------------------------------------------
// Fused kernel: conv+bn+relu+pool  ->  A-tile to global (L2-hot)  ->
//               GEMM (A via s_load, bit-identical FMA chain)  ->
//               exact rank-103 threshold (register-resident bisection).
//
// LDS plan (74 KB, 2 blocks/CU -> 8 waves/SIMD):
//   smem[18432] floats, time-multiplexed:
//     conv phase : xs = smem[0..12544)   (16 imgs x 784)
//                  hs = smem[12544..17984) (320 x 17 k-major staging)
//     epilogue   : zb = smem[0..16384)   (8 rows x 2048, XOR-swizzled chunks)
//   Phases separated by __syncthreads() (full vmcnt/lgkmcnt drain).
//
// Ht round-trips through GLOBAL memory (not LDS) to keep the A-path on the
// scalar cache: 16 waves share each 64B line via sL1; writes reach L2 before
// the barrier, s_loads read L2 (sL1 holds no stale copy: these lines are
// never scalar-read earlier in the dispatch). Separate restrict'd write/read
// pointers keep the backend's noclobber check happy so s_load survives.
//
// Epilogue v3: zb stored in 16B chunks with bijective XOR swizzle
//   swz(c) = c ^ ((c>>3)&7)      (involution; applied on write AND read)
// so each lane's 32 row-values are 8 contiguous ds_read_b128 (conflict-free
// after swizzle) -> uint32x4 v4[8] stays in VGPRs (54 live < 64 cap).
// 32-step MSB bisection: count = ballot+popc (SGPR-uniform state).
// T = max{T : count(u>=T) >= 103} == exact 103rd-largest key;
// (u >= T) == reference tie semantics (z >= topv[:,-1]).
// ---------------------------------------------------------------------------
__global__ __launch_bounds__(GTHREADS, 8) void fused_conv_gemm_topk(
    const float* __restrict__ x,
    const float* __restrict__ cw,
    const float* __restrict__ gamma,
    const float* __restrict__ beta,
    const float* __restrict__ mean,
    const float* __restrict__ var,
    float* __restrict__ HtW,            // A-tile write path
    const float* __restrict__ HtR,      // A-tile read path (same memory, fenced)
    const float* __restrict__ WT,
    float* __restrict__ out) {
#pragma clang fp contract(off)
  __shared__ __attribute__((aligned(16))) float smem[18432];  // 73728 B
  __shared__ float wv[45];
  __shared__ float inv_s[5], mu_s[5], be_s[5];
  __shared__ unsigned thr_s[BM];

  float* const xs = smem;              // 12544 floats
  float* const hs = smem + 12544;      // 5440 floats
  float* const zb = smem;              // 16384 floats (epilogue reuse)

  const int t    = threadIdx.x;
  const int lane = t & 63;
  const int w    = t >> 6;             // wave 0..15
  const int b0   = blockIdx.x * CIMG;

  // ==== phase 0: conv3x3 + BN + ReLU + maxpool3x3/3 for 16 images =========
  {
    const float4* src = (const float4*)(x + (size_t)b0 * 784);
    float4* dst = (float4*)xs;
    for (int i = t; i < CIMG * 196; i += GTHREADS) dst[i] = src[i];
  }
  if (t < 45) wv[t] = cw[t];
  if (t < 5) {
    inv_s[t] = gamma[t] / sqrtf(var[t] + 1e-5f);  // IEEE div & sqrt
    mu_s[t] = mean[t];
    be_s[t] = beta[t];
  }
  __syncthreads();

  {
    const int img = w;                  // one image per wave
    const float* xb = xs + img * 784;
    const int py = lane >> 3;
    const int px = lane & 7;

    float xr[5][5];
#pragma unroll
    for (int i = 0; i < 5; ++i)
#pragma unroll
      for (int j = 0; j < 5; ++j)
        xr[i][j] = xb[(3 * py + i) * 28 + 3 * px + j];

#pragma unroll
    for (int c = 0; c < 5; ++c) {
      float wr[9];
#pragma unroll
      for (int i = 0; i < 9; ++i) wr[i] = wv[c * 9 + i];
      const float inv = inv_s[c], mu = mu_s[c], be = be_s[c];
      float mx = -__builtin_huge_valf();
#pragma unroll
      for (int ry = 0; ry < 3; ++ry)
#pragma unroll
        for (int rx = 0; rx < 3; ++rx) {
          float s = 0.0f;
#pragma unroll
          for (int di = 0; di < 3; ++di)
#pragma unroll
            for (int dj = 0; dj < 3; ++dj)
              s = __builtin_fmaf(xr[ry + di][rx + dj], wr[di * 3 + dj], s);
          float t1 = s - mu;
          float t2 = t1 * inv;
          float t3 = t2 + be;
          mx = fmaxf(mx, t3);
        }
      hs[(c * 64 + lane) * 17 + img] = fmaxf(mx, 0.0f);
    }
  }
  __syncthreads();

  // ==== phase 1: A-tile -> global (coalesced; stays L2-hot) ===============
  {
    float* dst = HtW + (size_t)blockIdx.x * (KDIM * CIMG);
    for (int i = t; i < KDIM * CIMG; i += GTHREADS) {
      const int k = i >> 4;
      const int img = i & 15;
      dst[i] = hs[k * 17 + img];
    }
  }
  __syncthreads();   // compiler drains vmcnt before s_barrier -> stores in L2

  // ==== phase 2: GEMM main loop (bit-identical to passing rounds) =========
  const int m0 = blockIdx.x * BM;
  const int nt = t * 2;

  float acc[BM][2];
#pragma unroll
  for (int m = 0; m < BM; ++m) {
    acc[m][0] = 0.0f;
    acc[m][1] = 0.0f;
  }

  const float* Ap = HtR + (size_t)blockIdx.x * (KDIM * BM);  // A(k,m)=Ap[k*16+m]
  const float* wp = WT + nt;

#pragma unroll 4
  for (int k = 0; k < KDIM; ++k) {
    const float* ak = Ap + (size_t)k * BM;
    float av[BM];
#pragma unroll
    for (int m = 0; m < BM; ++m) av[m] = ak[m];   // uniform -> s_load (SGPRs)
    const float2 bb = *(const float2*)(wp + (size_t)k * EMB);
#pragma unroll
    for (int m = 0; m < BM; ++m) {
      acc[m][0] = __builtin_fmaf(av[m], bb.x, acc[m][0]);
      acc[m][1] = __builtin_fmaf(av[m], bb.y, acc[m][1]);
    }
  }

  // ==== phase 3: exact rank-KACT threshold, two half-tiles ================
  // chunk swizzle helpers (16B chunks, 512 per row)
  const int cW  = t >> 1;
  const int cWs = cW ^ ((cW >> 3) & 7);
  char* const zbase = (char*)zb;
  char* const wbase = zbase + (size_t)cWs * 16 + (size_t)(t & 1) * 8;

  // ---- half A: rows 8..15 (store first -> hi acc dies, frees VGPRs)
#pragma unroll
  for (int m = 0; m < 8; ++m)
    *(float2*)(wbase + (size_t)m * 8192) = *(const float2*)&acc[8 + m][0];
  __syncthreads();

  if (w >= 8) {
    const char* rowb = zbase + (size_t)(w - 8) * 8192;
    uint32x4 v4[8];
#pragma unroll
    for (int j = 0; j < 8; ++j) {
      const int c  = (lane << 3) | j;
      const int cs = c ^ (lane & 7);          // (c>>3)&7 == lane&7
      uint32x4 u = *(const uint32x4*)(rowb + (size_t)cs * 16);
#pragma unroll
      for (int e = 0; e < 4; ++e)
        u[e] = u[e] ^ (unsigned)(((int)u[e] >> 31) | 0x80000000);  // order map
      v4[j] = u;
      asm volatile("" : "+v"(v4[j]));         // pin to VGPRs (no LDS remat)
    }
    unsigned T = 0u;
    for (int b = 31; b >= 0; --b) {
      const unsigned cand = T | (1u << b);
      unsigned cnt = 0u;
#pragma unroll
      for (int j = 0; j < 8; ++j) {
        cnt += (unsigned)__popcll(__ballot(v4[j][0] >= cand));
        cnt += (unsigned)__popcll(__ballot(v4[j][1] >= cand));
        cnt += (unsigned)__popcll(__ballot(v4[j][2] >= cand));
        cnt += (unsigned)__popcll(__ballot(v4[j][3] >= cand));
      }
      if (cnt >= KACT) T = cand;              // wave-uniform (SGPR) update
    }
    if (lane == 0) thr_s[w] = T;              // row m0 + w  (w in 8..15)
  }
  __syncthreads();

#pragma unroll
  for (int m = 0; m < 8; ++m) {
    const float2 p = *(const float2*)(wbase + (size_t)m * 8192);
    const unsigned thr = thr_s[8 + m];
    unsigned ux = __float_as_uint(p.x); ux ^= (unsigned)(((int)ux >> 31) | 0x80000000);
    unsigned uy = __float_as_uint(p.y); uy ^= (unsigned)(((int)uy >> 31) | 0x80000000);
    float2 o;
    o.x = (ux >= thr) ? 1.0f : 0.0f;          // tie semantics: z >= topv[:,-1]
    o.y = (uy >= thr) ? 1.0f : 0.0f;
    *(float2*)(out + (size_t)(m0 + 8 + m) * EMB + nt) = o;
  }
  __syncthreads();   // all zb reads done before half B overwrites

  // ---- half B: rows 0..7
#pragma unroll
  for (int m = 0; m < 8; ++m)
    *(float2*)(wbase + (size_t)m * 8192) = *(const float2*)&acc[m][0];
  __syncthreads();

  if (w < 8) {
    const char* rowb = zbase + (size_t)w * 8192;
    uint32x4 v4[8];
#pragma unroll
    for (int j = 0; j < 8; ++j) {
      const int c  = (lane << 3) | j;
      const int cs = c ^ (lane & 7);
      uint32x4 u = *(const uint32x4*)(rowb + (size_t)cs * 16);
#pragma unroll
      for (int e = 0; e < 4; ++e)
        u[e] = u[e] ^ (unsigned)(((int)u[e] >> 31) | 0x80000000);
      v4[j] = u;
      asm volatile("" : "+v"(v4[j]));
    }
    unsigned T = 0u;
    for (int b = 31; b >= 0; --b) {
      const unsigned cand = T | (1u << b);
      unsigned cnt = 0u;
#pragma unroll
      for (int j = 0; j < 8; ++j) {
        cnt += (unsigned)__popcll(__ballot(v4[j][0] >= cand));
        cnt += (unsigned)__popcll(__ballot(v4[j][1] >= cand));
        cnt += (unsigned)__popcll(__ballot(v4[j][2] >= cand));
        cnt += (unsigned)__popcll(__ballot(v4[j][3] >= cand));
      }
      if (cnt >= KACT) T = cand;
    }
    if (lane == 0) thr_s[w] = T;              // row m0 + w  (w in 0..7)
  }
  __syncthreads();

#pragma unroll
  for (int m = 0; m < 8; ++m) {
    const float2 p = *(const float2*)(wbase + (size_t)m * 8192);
    const unsigned thr = thr_s[m];
    unsigned ux = __float_as_uint(p.x); ux ^= (unsigned)(((int)ux >> 31) | 0x80000000);
    unsigned uy = __float_as_uint(p.y); uy ^= (unsigned)(((int)uy >> 31) | 0x80000000);
    float2 o;
    o.x = (ux >= thr) ? 1.0f : 0.0f;
    o.y = (uy >= thr) ? 1.0f : 0.0f;
    *(float2*)(out + (size_t)(m0 + m) * EMB + nt) = o;
  }
}

// ---------------------------------------------------------------------------
extern "C" void kernel_launch(void* const* d_in, const int* in_sizes, int n_in,
                              void* d_out, int out_size, void* d_ws, size_t ws_size,
                              hipStream_t stream) {
  const float* x      = (const float*)d_in[0];
  const float* conv_w = (const float*)d_in[1];
  const float* gamma  = (const float*)d_in[2];
  const float* beta   = (const float*)d_in[3];
  const float* mean   = (const float*)d_in[4];
  const float* var    = (const float*)d_in[5];
  const float* fc_w   = (const float*)d_in[6];
  float* out = (float*)d_out;

  // workspace: Ht tile-major (2048 tiles x 320 x 16 f32 = 40 MB) | WT (320x2048)
  float* Ht = (float*)d_ws;
  float* WT = (float*)d_ws + (size_t)KDIM * BATCH;

  transpose_w_kernel<<<dim3(KDIM / 32, EMB / 32), dim3(32, 8), 0, stream>>>(fc_w, WT);
  fused_conv_gemm_topk<<<BATCH / CIMG, GTHREADS, 0, stream>>>(
      x, conv_w, gamma, beta, mean, var, Ht, Ht, WT, out);
}